// Round 4
// baseline (16455.948 us; speedup 1.0000x reference)
//
#include <hip/hip_runtime.h>
#include <hip/hip_cooperative_groups.h>
#include <math.h>

namespace cg = cooperative_groups;

#define T_STEPS 64
#define BATCH   16
#define IFACE_N 471
#define EPS_    1e-6f

#define GRID_BLOCKS   256
#define BLOCK_THREADS 256
#define TOT_THREADS   (GRID_BLOCKS * BLOCK_THREADS)

// iface column offsets
#define OFF_RK 0
#define OFF_RB 256
#define OFF_WK 260
#define OFF_WB 324
#define OFF_EV 325
#define OFF_WV 389
#define OFF_FG 453
#define OFF_AG 457
#define OFF_WG 458
#define OFF_RM 459

__device__ __forceinline__ float sigmoidf_(float x) { return 1.f / (1.f + expf(-x)); }
__device__ __forceinline__ float oneplusf_(float x) {
    return 1.f + fmaxf(x, 0.f) + log1pf(expf(-fabsf(x)));
}
__device__ __forceinline__ float wsum_(float v) {
#pragma unroll
    for (int off = 32; off > 0; off >>= 1) v += __shfl_xor(v, off, 64);
    return v;
}
__device__ __forceinline__ float wmax_(float v) {
#pragma unroll
    for (int off = 32; off > 0; off >>= 1) v = fmaxf(v, __shfl_xor(v, off, 64));
    return v;
}

// __launch_bounds__(256, 4): cap VGPRs at 128 so 4 workgroups/CU are resident.
// R2 (512 blk) and R3 (256 blk, no bound) never launched: heavy fused phases
// pushed VGPR>256 -> 1 block/CU -> hipLaunchCooperativeKernel rejects the grid
// (silent, since the return code isn't checked by the harness path).
__global__ void __launch_bounds__(BLOCK_THREADS, 4)
neucom_kernel(const float* __restrict__ x, const float* __restrict__ W_hid,
              const float* __restrict__ b_hid, const float* __restrict__ W_iface,
              const float* __restrict__ W_out, const float* __restrict__ W_memout,
              float* __restrict__ out, float* __restrict__ ws) {
    cg::grid_group grid = cg::this_grid();
    const int tid  = threadIdx.x;
    const int blk  = blockIdx.x;
    const int gtid = blk * BLOCK_THREADS + tid;
    const int wv   = tid >> 6;
    const int lane = tid & 63;

    // workspace layout (floats) — total 1,527,296 floats = 6.11 MB
    float* rv    = ws;                 // 4096   (B,R,W)
    float* hbuf  = rv + 4096;          // 8192   (B,H)
    float* pre   = hbuf + 8192;        // 8192   (B,O)
    float* ifc   = pre + 8192;         // 7680   (B,471 padded)
    float* u     = ifc + 7680;         // 4096   (B,N)
    float* pp    = u + 4096;           // 8192   two (B,N) ping-pong
    float* wwv   = pp + 8192;          // 4096   (B,N)
    float* rwv   = wwv + 4096;         // 16384  (B,R,N)
    float* rcg   = rwv + 16384;        // 16384  (B,R,N) read-content logits
    float* Mnorm = rcg + 16384;        // 4096   1/(||Mrow||+eps)
    float* knr   = Mnorm + 4096;       // 4096   normalized read keys (B,R,W)
    float* fwd4  = knr + 4096;         // 65536  (B,R,N,4) tile partials
    float* bwd4  = fwd4 + 65536;       // 65536
    float* M     = bwd4 + 65536;       // 262144 (B,N,W)
    float* L     = M + 262144;         // 1048576 (B,N,N)

    __shared__ float smf[4672];
    __shared__ int   smi[256];

    const float MNORM0 = 1.f / (sqrtf(64.f * 1e-6f * 1e-6f) + EPS_);

    // ---- init state (ws poisoned 0xAA each call) ----
    for (int i = gtid; i < 4096; i += TOT_THREADS) {
        rv[i] = 0.f; u[i] = 0.f; wwv[i] = 0.f; Mnorm[i] = MNORM0;
    }
    for (int i = gtid; i < 8192; i += TOT_THREADS) pp[i] = 0.f;
    for (int i = gtid; i < 16384; i += TOT_THREADS) rwv[i] = 0.f;
    for (int i = gtid; i < 262144; i += TOT_THREADS) M[i] = 1e-6f;
    for (int i = gtid; i < 1048576; i += TOT_THREADS) L[i] = 0.f;
    grid.sync();

    for (int t = 0; t < T_STEPS; t++) {
        float* pA = pp + (t & 1) * 4096;
        float* pB = pp + ((t + 1) & 1) * 4096;

        // ================= P0: h GEMV (blk<128) | out(t-1) GEMV (128..255) ====
        if (blk < 128) {
            int b = blk >> 3;
            for (int i = tid; i < 768; i += 256) {
                int sub = i / 192, k = i - sub * 192;
                smf[sub * 193 + k] = (i < 512) ? x[((size_t)t * BATCH + b) * 512 + i]
                                               : rv[b * 256 + (i - 512)];
            }
            __syncthreads();
            int g = (blk & 7) * 4 + wv;
            int l16 = lane & 15, sub = lane >> 4;
            int c = g * 16 + l16;
            const float* Wp = W_hid + (size_t)(sub * 192) * 512 + c;
            const float* sp = smf + sub * 193;
            float acc = 0.f;
#pragma unroll 8
            for (int k = 0; k < 192; k++) acc = fmaf(sp[k], Wp[(size_t)k * 512], acc);
            acc += __shfl_xor(acc, 16, 64);
            acc += __shfl_xor(acc, 32, 64);
            if (sub == 0) hbuf[b * 512 + c] = fmaxf(acc + b_hid[c], 0.f);
        } else {
            int q = blk - 128, b = q >> 3;
            {
                int sub = tid >> 6, k = tid & 63;
                smf[sub * 65 + k] = rv[b * 256 + tid];
            }
            __syncthreads();
            if (t > 0) {
                int g = (q & 7) * 4 + wv, l16 = lane & 15, sub = lane >> 4;
                int c = g * 16 + l16;
                const float* Wp = W_memout + (size_t)(sub * 64) * 512 + c;
                const float* sp = smf + sub * 65;
                float acc = 0.f;
#pragma unroll 8
                for (int k = 0; k < 64; k++) acc = fmaf(sp[k], Wp[(size_t)k * 512], acc);
                acc += __shfl_xor(acc, 16, 64);
                acc += __shfl_xor(acc, 32, 64);
                if (sub == 0) out[(size_t)(t - 1) * 8192 + b * 512 + c] = pre[b * 512 + c] + acc;
            }
        }
        grid.sync();

        // ================= P1: pre GEMV (blk<128) | iface GEMV (128..255) =====
        if (blk < 128) {
            int b = blk >> 3;
            for (int i = tid; i < 512; i += 256) {
                int sub = i >> 7, k = i & 127;
                smf[sub * 129 + k] = hbuf[b * 512 + i];
            }
            __syncthreads();
            int g = (blk & 7) * 4 + wv, l16 = lane & 15, sub = lane >> 4;
            int c = g * 16 + l16;
            const float* Wp = W_out + (size_t)(sub * 128) * 512 + c;
            const float* sp = smf + sub * 129;
            float acc = 0.f;
#pragma unroll 8
            for (int k = 0; k < 128; k++) acc = fmaf(sp[k], Wp[(size_t)k * 512], acc);
            acc += __shfl_xor(acc, 16, 64);
            acc += __shfl_xor(acc, 32, 64);
            if (sub == 0) pre[b * 512 + c] = acc;
        } else {
            int q = blk - 128, b = q >> 3;
            for (int i = tid; i < 512; i += 256) {
                int sub = i >> 7, k = i & 127;
                smf[sub * 129 + k] = hbuf[b * 512 + i];
            }
            __syncthreads();
            int g = (q & 7) * 4 + wv;
            if (g < 30) {
                int l16 = lane & 15, sub = lane >> 4;
                int c = g * 16 + l16;
                int ce = (c < IFACE_N) ? c : (IFACE_N - 1);
                const float* Wp = W_iface + (size_t)(sub * 128) * IFACE_N + ce;
                const float* sp = smf + sub * 129;
                float acc = 0.f;
#pragma unroll 8
                for (int k = 0; k < 128; k++) acc = fmaf(sp[k], Wp[(size_t)k * IFACE_N], acc);
                acc += __shfl_xor(acc, 16, 64);
                acc += __shfl_xor(acc, 32, 64);
                if (sub == 0 && c < IFACE_N) ifc[b * IFACE_N + c] = acc;
            }
        }
        grid.sync();

        // ================= P2 (blocks 0..15): usage, sort/alloc, write content, ww, p ===
        if (blk < BATCH) {
            int b = blk, n = tid;
            const float* ifb = ifc + b * IFACE_N;
            float* skey  = smf;          // 256
            float* sscan = smf + 256;    // 256
            float* sa    = smf + 512;    // 256
            float* scw   = smf + 768;    // 256
            float* red   = smf + 1024;   // 256
            float* knl   = smf + 1280;   // 64

            // normalized read keys -> knr (used in P3's rcg)
            {
                float kv = ifb[OFF_RK + tid];
                float ss = wsum_(kv * kv);
                knr[b * 256 + tid] = kv / (sqrtf(ss) + EPS_);
            }

            // retention & usage
            float ret = 1.f;
#pragma unroll
            for (int r = 0; r < 4; r++) {
                float fg = sigmoidf_(ifb[OFF_FG + r]);
                ret *= (1.f - fg * rwv[b * 1024 + r * 256 + n]);
            }
            float uo = u[b * 256 + n], wo = wwv[b * 256 + n];
            float un = (uo + wo - uo * wo) * ret;
            u[b * 256 + n] = un;

            // stable bitonic argsort ascending (index tie-break == stable argsort)
            skey[n] = un;
            smi[n]  = n;
            __syncthreads();
            for (int k = 2; k <= 256; k <<= 1) {
                for (int j = k >> 1; j > 0; j >>= 1) {
                    int ixj = n ^ j;
                    if (ixj > n) {
                        float a = skey[n], c2 = skey[ixj];
                        int ia = smi[n], ic = smi[ixj];
                        bool agtb = (a > c2) || (a == c2 && ia > ic);
                        bool up = ((n & k) == 0);
                        if (agtb == up) {
                            skey[n] = c2; skey[ixj] = a;
                            smi[n] = ic;  smi[ixj] = ia;
                        }
                    }
                    __syncthreads();
                }
            }
            // inclusive product scan of sorted usage
            sscan[n] = skey[n];
            __syncthreads();
            for (int off = 1; off < 256; off <<= 1) {
                float prev = (n >= off) ? sscan[n - off] : 1.f;
                __syncthreads();
                sscan[n] *= prev;
                __syncthreads();
            }
            float cpex  = (n == 0) ? 1.f : sscan[n - 1];
            float asort = (1.f - skey[n]) * cpex;
            sa[smi[n]] = asort;

            // write-key normalize (wave 0)
            if (n < 64) {
                float kv = ifb[OFF_WK + n];
                float ss = wsum_(kv * kv);
                knl[n] = kv / (sqrtf(ss) + EPS_);
            }
            __syncthreads();

            // content sim over OLD M (Mnorm from prev step / init)
            float wb = oneplusf_(ifb[OFF_WB]);
            for (int rr = 0; rr < 64; rr++) {
                int row = rr * 4 + wv;
                float Mv = M[(size_t)b * 16384 + row * 64 + lane];
                float dt = wsum_(Mv * knl[lane]);
                if (lane == 0) scw[row] = wb * dt * Mnorm[b * 256 + row];
            }
            __syncthreads();

            // wave-parallel softmax over 256 slots
            float v0 = scw[lane], v1 = scw[64 + lane], v2 = scw[128 + lane], v3 = scw[192 + lane];
            float mx = wmax_(fmaxf(fmaxf(v0, v1), fmaxf(v2, v3)));
            float e0 = expf(v0 - mx), e1 = expf(v1 - mx), e2 = expf(v2 - mx), e3 = expf(v3 - mx);
            float ssum = wsum_(e0 + e1 + e2 + e3);
            float vo = (wv == 0) ? v0 : (wv == 1) ? v1 : (wv == 2) ? v2 : v3;
            float cwn = expf(vo - mx) / ssum;

            float ag = sigmoidf_(ifb[OFF_AG]);
            float wg = sigmoidf_(ifb[OFF_WG]);
            float wwn = wg * (ag * sa[n] + (1.f - ag) * cwn);
            wwv[b * 256 + n] = wwn;
            red[n] = wwn;
            __syncthreads();
            float wws = wsum_(red[lane] + red[64 + lane] + red[128 + lane] + red[192 + lane]);
            pB[b * 256 + n] = (1.f - wws) * pA[b * 256 + n] + wwn;
        }
        grid.sync();

        // ================= P3 (all blocks): L tile + fwd/bwd partials + M + rcg ====
        {
            int b = blk >> 4, rem = blk & 15, ti = rem >> 2, tj = rem & 3;
            // stage old-rw segments for partial dots
            smf[4160 + wv * 64 + lane] = rwv[b * 1024 + wv * 256 + ti * 64 + lane];
            smf[4416 + wv * 64 + lane] = rwv[b * 1024 + wv * 256 + tj * 64 + lane];
            // L tile update (64x64), keep in LDS
            int c = lane;
#pragma unroll
            for (int rr = 0; rr < 16; rr++) {
                int il = wv + rr * 4;
                int ig = ti * 64 + il, jg = tj * 64 + c;
                size_t idx = (size_t)b * 65536 + ig * 256 + jg;
                float lv  = L[idx];
                float wwi = wwv[b * 256 + ig];
                float wwj = wwv[b * 256 + jg];
                float pj  = pA[b * 256 + jg];
                float nv  = (1.f - wwi - wwj) * lv + wwi * pj;
                if (ig == jg) nv = 0.f;
                L[idx] = nv;
                smf[il * 65 + c] = nv;
            }
            // M update + new norms + read-content logits (rows blk*16 .. +15)
#pragma unroll 1
            for (int i = 0; i < 4; i++) {
                int row = blk * 16 + wv * 4 + i;
                int bb = row >> 8, nn = row & 255;
                float wwn = wwv[bb * 256 + nn];
                float evv = sigmoidf_(ifc[bb * IFACE_N + OFF_EV + lane]);
                float wvv = ifc[bb * IFACE_N + OFF_WV + lane];
                float old = M[(size_t)row * 64 + lane];
                float nv  = old * (1.f - wwn * evv) + wwn * wvv;
                M[(size_t)row * 64 + lane] = nv;
                float ss  = wsum_(nv * nv);
                float inv = 1.f / (sqrtf(ss) + EPS_);
                const float* kb = knr + bb * 256;
                float d0 = wsum_(nv * kb[lane]);
                float d1 = wsum_(nv * kb[64 + lane]);
                float d2 = wsum_(nv * kb[128 + lane]);
                float d3 = wsum_(nv * kb[192 + lane]);
                if (lane == 0) {
                    Mnorm[row] = inv;
                    const float* ifb = ifc + bb * IFACE_N;
                    rcg[bb * 1024 + 0 * 256 + nn] = oneplusf_(ifb[OFF_RB + 0]) * d0 * inv;
                    rcg[bb * 1024 + 1 * 256 + nn] = oneplusf_(ifb[OFF_RB + 1]) * d1 * inv;
                    rcg[bb * 1024 + 2 * 256 + nn] = oneplusf_(ifb[OFF_RB + 2]) * d2 * inv;
                    rcg[bb * 1024 + 3 * 256 + nn] = oneplusf_(ifb[OFF_RB + 3]) * d3 * inv;
                }
            }
            __syncthreads();
            // fwd/bwd partial dots from the LDS tile (2-way LDS aliasing = free)
            {
                int r = wv;
                float accB = 0.f, accF = 0.f;
#pragma unroll 8
                for (int k = 0; k < 64; k++) {
                    accB = fmaf(smf[k * 65 + lane],  smf[4160 + r * 64 + k], accB);
                    accF = fmaf(smf[lane * 65 + k],  smf[4416 + r * 64 + k], accF);
                }
                bwd4[(((b * 4 + r) * 256) + tj * 64 + lane) * 4 + ti] = accB;
                fwd4[(((b * 4 + r) * 256) + ti * 64 + lane) * 4 + tj] = accF;
            }
        }
        grid.sync();

        // ================= P4 (blocks 0..15): rc softmax, rw_new, rv_new =====
        if (blk < BATCH) {
            int b = blk;
            const float* ifb = ifc + b * IFACE_N;
            float* src = smf;          // 1024
            float* srw = smf + 1024;   // 1024
            {
                int r = wv;
                const float* rg = rcg + b * 1024 + r * 256;
                float v0 = rg[lane], v1 = rg[64 + lane], v2 = rg[128 + lane], v3 = rg[192 + lane];
                float mx = wmax_(fmaxf(fmaxf(v0, v1), fmaxf(v2, v3)));
                float e0 = expf(v0 - mx), e1 = expf(v1 - mx), e2 = expf(v2 - mx), e3 = expf(v3 - mx);
                float s = wsum_(e0 + e1 + e2 + e3);
                float inv = 1.f / s;
                src[r * 256 + lane]       = e0 * inv;
                src[r * 256 + 64 + lane]  = e1 * inv;
                src[r * 256 + 128 + lane] = e2 * inv;
                src[r * 256 + 192 + lane] = e3 * inv;
            }
            __syncthreads();
            int n = tid;
            const float4* f4 = (const float4*)fwd4;
            const float4* b4 = (const float4*)bwd4;
#pragma unroll 1
            for (int r = 0; r < 4; r++) {
                float e0 = ifb[OFF_RM + r * 3 + 0];
                float e1 = ifb[OFF_RM + r * 3 + 1];
                float e2 = ifb[OFF_RM + r * 3 + 2];
                float mx = fmaxf(e0, fmaxf(e1, e2));
                float x0 = expf(e0 - mx), x1 = expf(e1 - mx), x2 = expf(e2 - mx);
                float inv = 1.f / (x0 + x1 + x2);
                float4 bv = b4[(b * 4 + r) * 256 + n];
                float4 fv = f4[(b * 4 + r) * 256 + n];
                float bwd_val = (bv.x + bv.y) + (bv.z + bv.w);
                float fwd_val = (fv.x + fv.y) + (fv.z + fv.w);
                float val = x0 * inv * bwd_val + x1 * inv * src[r * 256 + n] + x2 * inv * fwd_val;
                srw[r * 256 + n] = val;
                rwv[b * 1024 + r * 256 + n] = val;
            }
            __syncthreads();
            {
                int r = wv, w = lane;
                float acc0 = 0.f, acc1 = 0.f;
#pragma unroll 8
                for (int nn = 0; nn < 256; nn += 2) {
                    acc0 = fmaf(M[(size_t)b * 16384 + nn * 64 + w], srw[r * 256 + nn], acc0);
                    acc1 = fmaf(M[(size_t)b * 16384 + (nn + 1) * 64 + w], srw[r * 256 + nn + 1], acc1);
                }
                rv[b * 256 + r * 64 + w] = acc0 + acc1;
            }
        }
        grid.sync();
    }

    // ======== epilogue: out(T-1) ========
    if (blk >= 128) {
        int q = blk - 128, b = q >> 3;
        {
            int sub = tid >> 6, k = tid & 63;
            smf[sub * 65 + k] = rv[b * 256 + tid];
        }
        __syncthreads();
        int g = (q & 7) * 4 + wv, l16 = lane & 15, sub = lane >> 4;
        int c = g * 16 + l16;
        const float* Wp = W_memout + (size_t)(sub * 64) * 512 + c;
        const float* sp = smf + sub * 65;
        float acc = 0.f;
#pragma unroll 8
        for (int k = 0; k < 64; k++) acc = fmaf(sp[k], Wp[(size_t)k * 512], acc);
        acc += __shfl_xor(acc, 16, 64);
        acc += __shfl_xor(acc, 32, 64);
        if (sub == 0) out[(size_t)(T_STEPS - 1) * 8192 + b * 512 + c] = pre[b * 512 + c] + acc;
    }
}

extern "C" void kernel_launch(void* const* d_in, const int* in_sizes, int n_in,
                              void* d_out, int out_size, void* d_ws, size_t ws_size,
                              hipStream_t stream) {
    (void)in_sizes; (void)n_in; (void)out_size; (void)ws_size;
    const float* x        = (const float*)d_in[0];
    const float* W_hid    = (const float*)d_in[1];
    const float* b_hid    = (const float*)d_in[2];
    const float* W_iface  = (const float*)d_in[3];
    const float* W_out    = (const float*)d_in[4];
    const float* W_memout = (const float*)d_in[5];
    float* outp = (float*)d_out;
    float* wsp  = (float*)d_ws;

    void* args[] = {&x, &W_hid, &b_hid, &W_iface, &W_out, &W_memout, &outp, &wsp};
    hipLaunchCooperativeKernel((void*)neucom_kernel, dim3(GRID_BLOCKS),
                               dim3(BLOCK_THREADS), args, 0, stream);
}

// Round 5
// 6207.935 us; speedup vs baseline: 2.6508x; 2.6508x over previous
//
#include <hip/hip_runtime.h>
#include <math.h>

#define T_STEPS 64
#define BATCH   16
#define IFACE_N 471
#define EPS_    1e-6f

// iface column offsets
#define OFF_RK 0
#define OFF_RB 256
#define OFF_WK 260
#define OFF_WB 324
#define OFF_EV 325
#define OFF_WV 389
#define OFF_FG 453
#define OFF_AG 457
#define OFF_WG 458
#define OFF_RM 459

__device__ __forceinline__ float sigmoidf_(float x){ return 1.f/(1.f+expf(-x)); }
__device__ __forceinline__ float oneplusf_(float x){ return 1.f+fmaxf(x,0.f)+log1pf(expf(-fabsf(x))); }
__device__ __forceinline__ float wsum_(float v){
#pragma unroll
  for(int off=32; off>0; off>>=1) v += __shfl_xor(v,off,64);
  return v;
}
__device__ __forceinline__ float wmax_(float v){
#pragma unroll
  for(int off=32; off>0; off>>=1) v = fmaxf(v,__shfl_xor(v,off,64));
  return v;
}

// One 1024-thread block per batch. Zero grid syncs (batches are independent);
// all cross-phase ordering is __syncthreads. Small state in LDS for all 64
// steps; M (64KB) and L (256KB) per-batch in global (block-private, L2-hot).
__global__ void __launch_bounds__(1024, 4)
neucom_kernel(const float* __restrict__ x, const float* __restrict__ W_hid,
              const float* __restrict__ b_hid, const float* __restrict__ W_iface,
              const float* __restrict__ W_out, const float* __restrict__ W_memout,
              float* __restrict__ out, float* __restrict__ ws)
{
  const int tid  = threadIdx.x;
  const int b    = blockIdx.x;
  const int wv   = tid >> 6;
  const int lane = tid & 63;

  float* Mg = ws + (size_t)b * 16384;                 // (256,64)
  float* Lg = ws + 262144 + (size_t)b * 65536;        // (256,256)

  __shared__ float nnin[768];
  __shared__ float psum[2][520];
  __shared__ float hl[512];
  __shared__ float prel[512];
  __shared__ float ifcl[472];
  __shared__ float ul[256];
  __shared__ float pbuf[512];        // p ping-pong
  __shared__ float wwl[256];
  __shared__ float rwl[1024];        // (R,N)
  __shared__ float rvl[256];         // (R,W)
  __shared__ alignas(16) float evl[64];
  __shared__ alignas(16) float wvl[64];
  __shared__ float wkn[64];
  __shared__ float rkn[256];
  __shared__ float ssorted[256];
  __shared__ int   sidx[256];
  __shared__ float sal[256];
  __shared__ float siml[256];
  __shared__ float fwdl[1024];
  __shared__ float bwdl[1024];
  __shared__ float rcs[1024];
  __shared__ alignas(16) float bb[16][260];   // bwd cross-wave partials

  // ---- init (block-private; no cross-block deps) ----
  for (int i = tid; i < 16384; i += 1024) Mg[i] = 1e-6f;
  for (int i = tid; i < 65536; i += 1024) Lg[i] = 0.f;
  if (tid < 256){ ul[tid]=0.f; wwl[tid]=0.f; rvl[tid]=0.f; pbuf[tid]=0.f; pbuf[256+tid]=0.f; }
  rwl[tid] = 0.f;
  __syncthreads();

  for (int t = 0; t < T_STEPS; t++) {
    float* pO = pbuf + (t & 1) * 256;
    float* pN = pbuf + ((t + 1) & 1) * 256;

    // ===== A: h = relu([x_t, rv] @ W_hid + b_hid), k-split 2 =====
    if (tid < 512)      nnin[tid] = x[(size_t)(t*BATCH + b)*512 + tid];
    else if (tid < 768) nnin[tid] = rvl[tid - 512];
    __syncthreads();
    {
      int c = tid & 511, half = tid >> 9;
      const float* Wp = W_hid + (size_t)(half*384)*512 + c;
      const float* np = nnin + half*384;
      float acc = 0.f;
#pragma unroll 8
      for (int k = 0; k < 384; k++) acc = fmaf(np[k], Wp[(size_t)k*512], acc);
      psum[half][c] = acc;
    }
    __syncthreads();
    if (tid < 512) hl[tid] = fmaxf(psum[0][tid] + psum[1][tid] + b_hid[tid], 0.f);
    __syncthreads();

    // ===== B: pre_out (cols 0..511) | iface (cols 0..470) =====
    if (tid < 512) {
      const float* Wp = W_out + tid;
      float acc = 0.f;
#pragma unroll 8
      for (int k = 0; k < 512; k++) acc = fmaf(hl[k], Wp[(size_t)k*512], acc);
      prel[tid] = acc;
    } else {
      int c = tid - 512;
      if (c < IFACE_N) {
        const float* Wp = W_iface + c;
        float acc = 0.f;
#pragma unroll 8
        for (int k = 0; k < 512; k++) acc = fmaf(hl[k], Wp[(size_t)k*IFACE_N], acc);
        ifcl[c] = acc;
      }
    }
    __syncthreads();

    // ===== C: usage update + aux (ev,wv,wk-norm,rk-norm) =====
    if (tid < 256) {
      float ret = 1.f;
#pragma unroll
      for (int r = 0; r < 4; r++) {
        float fg = sigmoidf_(ifcl[OFF_FG + r]);
        ret *= (1.f - fg * rwl[r*256 + tid]);
      }
      float uo = ul[tid], wo = wwl[tid];
      ul[tid] = (uo + wo - uo*wo) * ret;
    } else if (tid < 320) {            // wave 4
      evl[tid-256] = sigmoidf_(ifcl[OFF_EV + (tid-256)]);
    } else if (tid < 384) {            // wave 5
      wvl[tid-320] = ifcl[OFF_WV + (tid-320)];
    } else if (tid >= 448 && tid < 512) {  // wave 7 (full wave for wsum_)
      float kv = ifcl[OFF_WK + lane];
      float ss = wsum_(kv*kv);
      wkn[lane] = kv / (sqrtf(ss) + EPS_);
    } else if (tid >= 512 && tid < 768) {  // waves 8..11
      int r = wv - 8;
      float kv = ifcl[OFF_RK + r*64 + lane];
      float ss = wsum_(kv*kv);
      rkn[r*64 + lane] = kv / (sqrtf(ss) + EPS_);
    }
    __syncthreads();

    // ===== D: stable argsort (rank count, tie-break by index) + cumprod =====
    {
      int n = tid >> 2, q = tid & 3;
      float un = ul[n];
      const float* sp = ul + q*64;
      int cnt = 0;
#pragma unroll 8
      for (int m = 0; m < 64; m++) {
        float um = sp[m];
        int gm = q*64 + m;
        cnt += (um < un || (um == un && gm < n)) ? 1 : 0;
      }
      cnt += __shfl_xor(cnt, 1, 64);
      cnt += __shfl_xor(cnt, 2, 64);
      if (q == 0) { ssorted[cnt] = un; sidx[cnt] = n; }
    }
    __syncthreads();
    if (wv == 0) {   // exclusive cumprod over sorted usage, alloc scatter
      float carry = 1.f;
#pragma unroll
      for (int c2 = 0; c2 < 4; c2++) {
        float v0 = ssorted[c2*64 + lane];
        float v = v0;
#pragma unroll
        for (int off = 1; off < 64; off <<= 1) {
          float uu = __shfl_up(v, off, 64);
          if (lane >= off) v *= uu;
        }
        float e = __shfl_up(v, 1, 64);
        if (lane == 0) e = 1.f;
        sal[sidx[c2*64 + lane]] = (1.f - v0) * e * carry;
        carry *= __shfl(v, 63, 64);
      }
    }
    __syncthreads();

    // ===== E: write content weights (OLD M), ww, p_new =====
    {
      int n = tid >> 2, q = tid & 3;
      const float4* Mp = (const float4*)(Mg + n*64 + q*16);
      float ss = 0.f, dt = 0.f;
#pragma unroll
      for (int i = 0; i < 4; i++) {
        float4 mv = Mp[i];
        const float* kp = wkn + q*16 + i*4;
        ss += mv.x*mv.x + mv.y*mv.y + mv.z*mv.z + mv.w*mv.w;
        dt += mv.x*kp[0] + mv.y*kp[1] + mv.z*kp[2] + mv.w*kp[3];
      }
      ss += __shfl_xor(ss,1,64); ss += __shfl_xor(ss,2,64);
      dt += __shfl_xor(dt,1,64); dt += __shfl_xor(dt,2,64);
      if (q == 0) {
        float wb = oneplusf_(ifcl[OFF_WB]);
        siml[n] = wb * dt / (sqrtf(ss) + EPS_);
      }
    }
    __syncthreads();
    if (tid < 256) {
      float v0 = siml[lane], v1 = siml[64+lane], v2 = siml[128+lane], v3 = siml[192+lane];
      float mx = wmax_(fmaxf(fmaxf(v0,v1), fmaxf(v2,v3)));
      float ssum = wsum_(expf(v0-mx)+expf(v1-mx)+expf(v2-mx)+expf(v3-mx));
      float cw = expf(siml[tid]-mx) / ssum;
      float ag = sigmoidf_(ifcl[OFF_AG]);
      float wg = sigmoidf_(ifcl[OFF_WG]);
      wwl[tid] = wg * (ag*sal[tid] + (1.f-ag)*cw);
    }
    __syncthreads();
    if (tid < 256) {
      float s4 = wwl[lane] + wwl[64+lane] + wwl[128+lane] + wwl[192+lane];
      float wws = wsum_(s4);
      pN[tid] = (1.f - wws)*pO[tid] + wwl[tid];
    }
    __syncthreads();

    // ===== F: L update (rows wv*16..+15) + fwd (row dots) + bwd (col partials) =====
    {
      int j0 = lane*4;
      float wwj0 = wwl[j0], wwj1 = wwl[j0+1], wwj2 = wwl[j0+2], wwj3 = wwl[j0+3];
      float pj0 = pO[j0], pj1 = pO[j0+1], pj2 = pO[j0+2], pj3 = pO[j0+3];
      float rw00 = rwl[j0],     rw01 = rwl[j0+1],     rw02 = rwl[j0+2],     rw03 = rwl[j0+3];
      float rw10 = rwl[256+j0], rw11 = rwl[256+j0+1], rw12 = rwl[256+j0+2], rw13 = rwl[256+j0+3];
      float rw20 = rwl[512+j0], rw21 = rwl[512+j0+1], rw22 = rwl[512+j0+2], rw23 = rwl[512+j0+3];
      float rw30 = rwl[768+j0], rw31 = rwl[768+j0+1], rw32 = rwl[768+j0+2], rw33 = rwl[768+j0+3];
      float4 ba0 = {0,0,0,0}, ba1 = {0,0,0,0}, ba2 = {0,0,0,0}, ba3 = {0,0,0,0};
      float4* Lrow = (float4*)Lg;
#pragma unroll 4
      for (int ii = 0; ii < 16; ii++) {
        int i = wv*16 + ii;
        float wwi = wwl[i];
        float4 lv = Lrow[i*64 + lane];
        float4 nv;
        nv.x = (1.f - wwi - wwj0)*lv.x + wwi*pj0;
        nv.y = (1.f - wwi - wwj1)*lv.y + wwi*pj1;
        nv.z = (1.f - wwi - wwj2)*lv.z + wwi*pj2;
        nv.w = (1.f - wwi - wwj3)*lv.w + wwi*pj3;
        if (j0   == i) nv.x = 0.f;
        if (j0+1 == i) nv.y = 0.f;
        if (j0+2 == i) nv.z = 0.f;
        if (j0+3 == i) nv.w = 0.f;
        Lrow[i*64 + lane] = nv;
        // fwd[r,i] = sum_j Lnew[i,j]*rw[r,j]
        float f0 = nv.x*rw00 + nv.y*rw01 + nv.z*rw02 + nv.w*rw03;
        float f1 = nv.x*rw10 + nv.y*rw11 + nv.z*rw12 + nv.w*rw13;
        float f2 = nv.x*rw20 + nv.y*rw21 + nv.z*rw22 + nv.w*rw23;
        float f3 = nv.x*rw30 + nv.y*rw31 + nv.z*rw32 + nv.w*rw33;
        f0 = wsum_(f0); f1 = wsum_(f1); f2 = wsum_(f2); f3 = wsum_(f3);
        if (lane == 0) { fwdl[i] = f0; fwdl[256+i] = f1; fwdl[512+i] = f2; fwdl[768+i] = f3; }
        // bwd[r,j] += rw[r,i]*Lnew[i,j]   (lane-local, cols j0..j0+3)
        float ri0 = rwl[i], ri1 = rwl[256+i], ri2 = rwl[512+i], ri3 = rwl[768+i];
        ba0.x = fmaf(ri0, nv.x, ba0.x); ba0.y = fmaf(ri0, nv.y, ba0.y);
        ba0.z = fmaf(ri0, nv.z, ba0.z); ba0.w = fmaf(ri0, nv.w, ba0.w);
        ba1.x = fmaf(ri1, nv.x, ba1.x); ba1.y = fmaf(ri1, nv.y, ba1.y);
        ba1.z = fmaf(ri1, nv.z, ba1.z); ba1.w = fmaf(ri1, nv.w, ba1.w);
        ba2.x = fmaf(ri2, nv.x, ba2.x); ba2.y = fmaf(ri2, nv.y, ba2.y);
        ba2.z = fmaf(ri2, nv.z, ba2.z); ba2.w = fmaf(ri2, nv.w, ba2.w);
        ba3.x = fmaf(ri3, nv.x, ba3.x); ba3.y = fmaf(ri3, nv.y, ba3.y);
        ba3.z = fmaf(ri3, nv.z, ba3.z); ba3.w = fmaf(ri3, nv.w, ba3.w);
      }
      // head-staged cross-wave reduce of bwd partials
#pragma unroll
      for (int r = 0; r < 4; r++) {
        float4 v = (r==0) ? ba0 : (r==1) ? ba1 : (r==2) ? ba2 : ba3;
        *(float4*)&bb[wv][j0] = v;
        __syncthreads();
        if (tid < 256) {
          float s = 0.f;
#pragma unroll
          for (int w2 = 0; w2 < 16; w2++) s += bb[w2][tid];
          bwdl[r*256 + tid] = s;
        }
        __syncthreads();
      }
    }

    // ===== G: M update + new norms + read-content logits (NEW M) =====
    {
      int n = tid >> 2, q = tid & 3;
      float wwn = wwl[n];
      float4* Mp = (float4*)(Mg + n*64 + q*16);
      float ss = 0.f, d0 = 0.f, d1 = 0.f, d2 = 0.f, d3 = 0.f;
#pragma unroll
      for (int i = 0; i < 4; i++) {
        float4 mv = Mp[i];
        int w0 = q*16 + i*4;
        float4 ev = *(const float4*)(evl + w0);
        float4 wq = *(const float4*)(wvl + w0);
        float4 nv;
        nv.x = mv.x*(1.f - wwn*ev.x) + wwn*wq.x;
        nv.y = mv.y*(1.f - wwn*ev.y) + wwn*wq.y;
        nv.z = mv.z*(1.f - wwn*ev.z) + wwn*wq.z;
        nv.w = mv.w*(1.f - wwn*ev.w) + wwn*wq.w;
        Mp[i] = nv;
        ss += nv.x*nv.x + nv.y*nv.y + nv.z*nv.z + nv.w*nv.w;
        const float* k0 = rkn + w0;
        const float* k1 = rkn + 64 + w0;
        const float* k2 = rkn + 128 + w0;
        const float* k3 = rkn + 192 + w0;
        d0 += nv.x*k0[0] + nv.y*k0[1] + nv.z*k0[2] + nv.w*k0[3];
        d1 += nv.x*k1[0] + nv.y*k1[1] + nv.z*k1[2] + nv.w*k1[3];
        d2 += nv.x*k2[0] + nv.y*k2[1] + nv.z*k2[2] + nv.w*k2[3];
        d3 += nv.x*k3[0] + nv.y*k3[1] + nv.z*k3[2] + nv.w*k3[3];
      }
      ss += __shfl_xor(ss,1,64); ss += __shfl_xor(ss,2,64);
      d0 += __shfl_xor(d0,1,64); d0 += __shfl_xor(d0,2,64);
      d1 += __shfl_xor(d1,1,64); d1 += __shfl_xor(d1,2,64);
      d2 += __shfl_xor(d2,1,64); d2 += __shfl_xor(d2,2,64);
      d3 += __shfl_xor(d3,1,64); d3 += __shfl_xor(d3,2,64);
      if (q == 0) {
        float inv = 1.f/(sqrtf(ss) + EPS_);
        rcs[n]     = oneplusf_(ifcl[OFF_RB+0]) * d0 * inv;
        rcs[256+n] = oneplusf_(ifcl[OFF_RB+1]) * d1 * inv;
        rcs[512+n] = oneplusf_(ifcl[OFF_RB+2]) * d2 * inv;
        rcs[768+n] = oneplusf_(ifcl[OFF_RB+3]) * d3 * inv;
      }
    }
    __syncthreads();
    if (wv < 4) {   // rc softmax, in-place, one wave per head
      float* rp = rcs + wv*256;
      float v0 = rp[lane], v1 = rp[64+lane], v2 = rp[128+lane], v3 = rp[192+lane];
      float mx = wmax_(fmaxf(fmaxf(v0,v1), fmaxf(v2,v3)));
      float e0 = expf(v0-mx), e1 = expf(v1-mx), e2 = expf(v2-mx), e3 = expf(v3-mx);
      float inv = 1.f / wsum_(e0+e1+e2+e3);
      rp[lane] = e0*inv; rp[64+lane] = e1*inv; rp[128+lane] = e2*inv; rp[192+lane] = e3*inv;
    }
    __syncthreads();

    // ===== H: rw_new + rv_new =====
    {
      int r = tid >> 8;
      float e0 = ifcl[OFF_RM + r*3+0], e1 = ifcl[OFF_RM + r*3+1], e2 = ifcl[OFF_RM + r*3+2];
      float mx = fmaxf(e0, fmaxf(e1, e2));
      float x0 = expf(e0-mx), x1 = expf(e1-mx), x2 = expf(e2-mx);
      float inv = 1.f/(x0+x1+x2);
      rwl[tid] = (x0*bwdl[tid] + x1*rcs[tid] + x2*fwdl[tid]) * inv;
    }
    __syncthreads();
    if (wv < 4) {   // rv[r,w] = sum_n M[n,w]*rw[r,n]
      const float* rp = rwl + wv*256;
      float acc = 0.f;
#pragma unroll 4
      for (int n = 0; n < 256; n++) acc = fmaf(Mg[n*64 + lane], rp[n], acc);
      rvl[wv*64 + lane] = acc;
    }
    __syncthreads();

    // ===== I: out = pre + rv @ W_memout (k-split 2) =====
    {
      int c = tid & 511, half = tid >> 9;
      const float* Wp = W_memout + (size_t)(half*128)*512 + c;
      const float* rp = rvl + half*128;
      float acc = 0.f;
#pragma unroll 8
      for (int k = 0; k < 128; k++) acc = fmaf(rp[k], Wp[(size_t)k*512], acc);
      psum[half][c] = acc;
    }
    __syncthreads();
    if (tid < 512) out[(size_t)t*8192 + b*512 + tid] = prel[tid] + psum[0][tid] + psum[1][tid];
    __syncthreads();
  }
}

extern "C" void kernel_launch(void* const* d_in, const int* in_sizes, int n_in,
                              void* d_out, int out_size, void* d_ws, size_t ws_size,
                              hipStream_t stream) {
  (void)in_sizes; (void)n_in; (void)out_size; (void)ws_size;
  const float* x        = (const float*)d_in[0];
  const float* W_hid    = (const float*)d_in[1];
  const float* b_hid    = (const float*)d_in[2];
  const float* W_iface  = (const float*)d_in[3];
  const float* W_out    = (const float*)d_in[4];
  const float* W_memout = (const float*)d_in[5];
  float* outp = (float*)d_out;
  float* wsp  = (float*)d_ws;

  hipLaunchKernelGGL(neucom_kernel, dim3(BATCH), dim3(1024), 0, stream,
                     x, W_hid, b_hid, W_iface, W_out, W_memout, outp, wsp);
}

// Round 6
// 3457.977 us; speedup vs baseline: 4.7588x; 1.7953x over previous
//
#include <hip/hip_runtime.h>
#include <math.h>

#define TS 64
#define IFACE_N 471
#define IFS 480           // padded iface row stride
#define EPS_ 1e-6f

// iface column offsets
#define OFF_RK 0
#define OFF_RB 256
#define OFF_WK 260
#define OFF_WB 324
#define OFF_EV 325
#define OFF_WV 389
#define OFF_FG 453
#define OFF_AG 457
#define OFF_WG 458
#define OFF_RM 459

// ws float offsets
#define O_RV    0        // 4096
#define O_HBUF  4096     // 8192
#define O_PRE   12288    // 8192
#define O_IFC   20480    // 7680 (16 x 480)
#define O_U     28160    // 4096
#define O_PP    32256    // 8192 (2 x 4096)
#define O_WW    40448    // 4096
#define O_RW    44544    // 16384
#define O_KNR   60928    // 4096
#define O_FWD   65024    // 16384
#define O_BWD   81408    // 16384
#define O_RCG   97792    // 16384
#define O_M     114176   // 262144
#define O_L     376320   // 1048576
// total 1,424,896 floats = 5.70 MB

__device__ __forceinline__ float sigmoidf_(float x){ return 1.f/(1.f+expf(-x)); }
__device__ __forceinline__ float oneplusf_(float x){ return 1.f+fmaxf(x,0.f)+log1pf(expf(-fabsf(x))); }
__device__ __forceinline__ float wsum_(float v){
#pragma unroll
  for(int off=32; off>0; off>>=1) v += __shfl_xor(v,off,64);
  return v;
}
__device__ __forceinline__ float wmax_(float v){
#pragma unroll
  for(int off=32; off>0; off>>=1) v = fmaxf(v,__shfl_xor(v,off,64));
  return v;
}

// ===================== init =====================
__global__ void __launch_bounds__(256) kInit(float* ws){
  int g = blockIdx.x*256 + threadIdx.x;          // 65536 threads
  if (g < 4096){ ws[O_RV+g]=0.f; ws[O_U+g]=0.f; ws[O_WW+g]=0.f; }
  if (g < 8192) ws[O_PP+g]=0.f;
  if (g < 16384) ws[O_RW+g]=0.f;
  for (int i=g;i<262144;i+=65536) ws[O_M+i]=1e-6f;
  for (int i=g;i<1048576;i+=65536) ws[O_L+i]=0.f;
}

// ===================== kA: h GEMV (blk<128) | out(t-1) GEMV =====================
__global__ void __launch_bounds__(256)
kA(const float* __restrict__ x, const float* __restrict__ W_hid,
   const float* __restrict__ b_hid, const float* __restrict__ W_memout,
   float* __restrict__ ws, float* __restrict__ out, int t)
{
  const int tid = threadIdx.x, blk = blockIdx.x;
  const float* rvv = ws + O_RV;
  if (blk < 128) {
    if (t >= TS) return;
    int b = blk >> 3, c0 = (blk & 7) * 64;
    __shared__ float nn[768];
    __shared__ float4 ps[16][16];
    for (int i = tid; i < 768; i += 256)
      nn[i] = (i < 512) ? x[(size_t)(t*16+b)*512 + i] : rvv[b*256 + i - 512];
    __syncthreads();
    int fc = tid & 15, seg = tid >> 4;            // 16 segs x 48 k
    const float4* Wp = (const float4*)(W_hid + (size_t)(seg*48)*512 + c0) + fc;
    const float* np = nn + seg*48;
    float4 a = {0.f,0.f,0.f,0.f};
#pragma unroll 8
    for (int k = 0; k < 48; k++) {
      float s = np[k];
      float4 w = Wp[(size_t)k*128];
      a.x = fmaf(s,w.x,a.x); a.y = fmaf(s,w.y,a.y);
      a.z = fmaf(s,w.z,a.z); a.w = fmaf(s,w.w,a.w);
    }
    ps[seg][fc] = a;
    __syncthreads();
    if (tid < 16) {
      float4 s = ps[0][tid];
#pragma unroll
      for (int i = 1; i < 16; i++) {
        float4 v = ps[i][tid];
        s.x += v.x; s.y += v.y; s.z += v.z; s.w += v.w;
      }
      int c = c0 + tid*4;
      float* hb = ws + O_HBUF + b*512 + c;
      hb[0] = fmaxf(s.x + b_hid[c+0], 0.f);
      hb[1] = fmaxf(s.y + b_hid[c+1], 0.f);
      hb[2] = fmaxf(s.z + b_hid[c+2], 0.f);
      hb[3] = fmaxf(s.w + b_hid[c+3], 0.f);
    }
  } else {
    if (t == 0) return;
    int q = blk - 128, b = q >> 2, c0 = (q & 3) * 128;
    __shared__ float rl[256];
    __shared__ float4 ps[8][32];
    if (tid < 256) rl[tid] = rvv[b*256 + tid];
    __syncthreads();
    int fc = tid & 31, seg = tid >> 5;            // 8 segs x 32 k
    const float4* Wp = (const float4*)(W_memout + (size_t)(seg*32)*512 + c0) + fc;
    const float* rp = rl + seg*32;
    float4 a = {0.f,0.f,0.f,0.f};
#pragma unroll 8
    for (int k = 0; k < 32; k++) {
      float s = rp[k];
      float4 w = Wp[(size_t)k*128];
      a.x = fmaf(s,w.x,a.x); a.y = fmaf(s,w.y,a.y);
      a.z = fmaf(s,w.z,a.z); a.w = fmaf(s,w.w,a.w);
    }
    ps[seg][fc] = a;
    __syncthreads();
    if (tid < 32) {
      float4 s = ps[0][tid];
#pragma unroll
      for (int i = 1; i < 8; i++) {
        float4 v = ps[i][tid];
        s.x += v.x; s.y += v.y; s.z += v.z; s.w += v.w;
      }
      int c = c0 + tid*4;
      float4 pv = *(const float4*)(ws + O_PRE + b*512 + c);
      float4 o; o.x = pv.x+s.x; o.y = pv.y+s.y; o.z = pv.z+s.z; o.w = pv.w+s.w;
      *(float4*)(out + (size_t)(t-1)*8192 + b*512 + c) = o;
    }
  }
}

// ===================== kB: pre GEMV (blk<128) | iface GEMV =====================
__global__ void __launch_bounds__(256)
kB(const float* __restrict__ W_out, const float* __restrict__ W_iface,
   float* __restrict__ ws)
{
  const int tid = threadIdx.x, blk = blockIdx.x;
  if (blk < 128) {
    int b = blk >> 3, c0 = (blk & 7) * 64;
    __shared__ float hl[512];
    __shared__ float4 ps[16][16];
    for (int i = tid; i < 512; i += 256) hl[i] = ws[O_HBUF + b*512 + i];
    __syncthreads();
    int fc = tid & 15, seg = tid >> 4;            // 16 segs x 32 k
    const float4* Wp = (const float4*)(W_out + (size_t)(seg*32)*512 + c0) + fc;
    const float* hp = hl + seg*32;
    float4 a = {0.f,0.f,0.f,0.f};
#pragma unroll 8
    for (int k = 0; k < 32; k++) {
      float s = hp[k];
      float4 w = Wp[(size_t)k*128];
      a.x = fmaf(s,w.x,a.x); a.y = fmaf(s,w.y,a.y);
      a.z = fmaf(s,w.z,a.z); a.w = fmaf(s,w.w,a.w);
    }
    ps[seg][fc] = a;
    __syncthreads();
    if (tid < 16) {
      float4 s = ps[0][tid];
#pragma unroll
      for (int i = 1; i < 16; i++) {
        float4 v = ps[i][tid];
        s.x += v.x; s.y += v.y; s.z += v.z; s.w += v.w;
      }
      *(float4*)(ws + O_PRE + b*512 + c0 + tid*4) = s;
    }
  } else {
    int q = blk - 128, b = q >> 3, g = q & 7;
    int c0 = g * 60;
    int ncol = (c0 + 60 <= IFACE_N) ? 60 : (IFACE_N - c0);   // last group: 51
    __shared__ float hl[512];
    __shared__ float ps[4][64];
    for (int i = tid; i < 512; i += 256) hl[i] = ws[O_HBUF + b*512 + i];
    __syncthreads();
    int c = tid & 63, seg = tid >> 6;             // 4 segs x 128 k
    float acc = 0.f;
    if (c < ncol) {
      const float* Wp = W_iface + (size_t)(seg*128)*IFACE_N + c0 + c;
      const float* hp = hl + seg*128;
#pragma unroll 8
      for (int k = 0; k < 128; k++) acc = fmaf(hp[k], Wp[(size_t)k*IFACE_N], acc);
    }
    ps[seg][c] = acc;
    __syncthreads();
    if (tid < 64 && tid < ncol)
      ws[O_IFC + b*IFS + c0 + tid] = ps[0][tid] + ps[1][tid] + ps[2][tid] + ps[3][tid];
  }
}

// ===================== kC: usage, sort/alloc, write content, ww, p =====================
__global__ void __launch_bounds__(1024)
kC(float* __restrict__ ws, int t)
{
  const int tid = threadIdx.x, b = blockIdx.x;
  const int wv = tid >> 6, lane = tid & 63;
  const float* ifb = ws + O_IFC + b*IFS;
  const float* Mg  = ws + O_M + (size_t)b*16384;
  const float* pO  = ws + O_PP + (t&1)*4096 + b*256;
  float*       pN  = ws + O_PP + ((t+1)&1)*4096 + b*256;

  __shared__ float ul[256];
  __shared__ float wkn[64];
  __shared__ float ssorted[256];
  __shared__ int   sidx[256];
  __shared__ float sal[256];
  __shared__ float siml[256];
  __shared__ float wwst[256];

  // usage + key norms
  if (tid < 256) {
    float ret = 1.f;
#pragma unroll
    for (int r = 0; r < 4; r++) {
      float fg = sigmoidf_(ifb[OFF_FG + r]);
      ret *= (1.f - fg * ws[O_RW + b*1024 + r*256 + tid]);
    }
    float uo = ws[O_U + b*256 + tid], wo = ws[O_WW + b*256 + tid];
    float un = (uo + wo - uo*wo) * ret;
    ul[tid] = un;
    ws[O_U + b*256 + tid] = un;
  } else if (tid >= 448 && tid < 512) {                  // wave 7: wk norm
    float kv = ifb[OFF_WK + lane];
    float ss = wsum_(kv*kv);
    wkn[lane] = kv / (sqrtf(ss) + EPS_);
  } else if (tid >= 512 && tid < 768) {                  // waves 8..11: rk norms
    int r = wv - 8;
    float kv = ifb[OFF_RK + r*64 + lane];
    float ss = wsum_(kv*kv);
    ws[O_KNR + b*256 + r*64 + lane] = kv / (sqrtf(ss) + EPS_);
  }
  __syncthreads();

  // stable rank argsort + cumprod alloc
  {
    int n = tid >> 2, q = tid & 3;
    float un = ul[n];
    const float* sp = ul + q*64;
    int cnt = 0;
#pragma unroll 8
    for (int m = 0; m < 64; m++) {
      float um = sp[m];
      int gm = q*64 + m;
      cnt += (um < un || (um == un && gm < n)) ? 1 : 0;
    }
    cnt += __shfl_xor(cnt, 1, 64);
    cnt += __shfl_xor(cnt, 2, 64);
    if (q == 0) { ssorted[cnt] = un; sidx[cnt] = n; }
  }
  __syncthreads();
  if (wv == 0) {
    float carry = 1.f;
#pragma unroll
    for (int c2 = 0; c2 < 4; c2++) {
      float v0 = ssorted[c2*64 + lane];
      float v = v0;
#pragma unroll
      for (int off = 1; off < 64; off <<= 1) {
        float uu = __shfl_up(v, off, 64);
        if (lane >= off) v *= uu;
      }
      float e = __shfl_up(v, 1, 64);
      if (lane == 0) e = 1.f;
      sal[sidx[c2*64 + lane]] = (1.f - v0) * e * carry;
      carry *= __shfl(v, 63, 64);
    }
  }
  __syncthreads();

  // content sim over OLD M
  {
    int n = tid >> 2, q = tid & 3;
    const float4* Mp = (const float4*)(Mg + n*64 + q*16);
    float ss = 0.f, dt = 0.f;
#pragma unroll
    for (int i = 0; i < 4; i++) {
      float4 mv = Mp[i];
      const float* kp = wkn + q*16 + i*4;
      ss += mv.x*mv.x + mv.y*mv.y + mv.z*mv.z + mv.w*mv.w;
      dt += mv.x*kp[0] + mv.y*kp[1] + mv.z*kp[2] + mv.w*kp[3];
    }
    ss += __shfl_xor(ss,1,64); ss += __shfl_xor(ss,2,64);
    dt += __shfl_xor(dt,1,64); dt += __shfl_xor(dt,2,64);
    if (q == 0) {
      float wb = oneplusf_(ifb[OFF_WB]);
      siml[n] = wb * dt / (sqrtf(ss) + EPS_);
    }
  }
  __syncthreads();
  if (tid < 256) {
    float v0 = siml[lane], v1 = siml[64+lane], v2 = siml[128+lane], v3 = siml[192+lane];
    float mx = wmax_(fmaxf(fmaxf(v0,v1), fmaxf(v2,v3)));
    float ssum = wsum_(expf(v0-mx)+expf(v1-mx)+expf(v2-mx)+expf(v3-mx));
    float cw = expf(siml[tid]-mx) / ssum;
    float ag = sigmoidf_(ifb[OFF_AG]);
    float wg = sigmoidf_(ifb[OFF_WG]);
    float wwn = wg * (ag*sal[tid] + (1.f-ag)*cw);
    ws[O_WW + b*256 + tid] = wwn;
    wwst[tid] = wwn;
  }
  __syncthreads();
  if (tid < 256) {
    float s4 = wwst[lane] + wwst[64+lane] + wwst[128+lane] + wwst[192+lane];
    float wws = wsum_(s4);
    pN[tid] = (1.f - wws)*pO[tid] + wwst[tid];
  }
}

// ===================== kD: L update + fwd/bwd + M update + rc logits =====================
__global__ void __launch_bounds__(1024)
kD(float* __restrict__ ws, int t)
{
  const int tid = threadIdx.x, b = blockIdx.x;
  const int wv = tid >> 6, lane = tid & 63;
  const float* ifb = ws + O_IFC + b*IFS;
  float* Mg = ws + O_M + (size_t)b*16384;
  float* Lg = ws + O_L + (size_t)b*65536;

  __shared__ float wwl[256];
  __shared__ float pOl[256];
  __shared__ float rwl[1024];
  __shared__ float rknl[256];
  __shared__ alignas(16) float evl[64];
  __shared__ alignas(16) float wvl[64];
  __shared__ float fwdl[1024];
  __shared__ float bwdl[1024];
  __shared__ float rcs[1024];
  __shared__ alignas(16) float bb[16][260];

  rwl[tid] = ws[O_RW + b*1024 + tid];
  if (tid < 256)                 wwl[tid] = ws[O_WW + b*256 + tid];
  else if (tid < 512)            pOl[tid-256] = ws[O_PP + (t&1)*4096 + b*256 + tid-256];
  else if (tid < 576)            evl[tid-512] = sigmoidf_(ifb[OFF_EV + tid-512]);
  else if (tid < 640)            wvl[tid-576] = ifb[OFF_WV + tid-576];
  else if (tid < 896)            rknl[tid-640] = ws[O_KNR + b*256 + tid-640];
  __syncthreads();

  // L update + fwd + bwd partials
  {
    int j0 = lane*4;
    float wwj0 = wwl[j0], wwj1 = wwl[j0+1], wwj2 = wwl[j0+2], wwj3 = wwl[j0+3];
    float pj0 = pOl[j0], pj1 = pOl[j0+1], pj2 = pOl[j0+2], pj3 = pOl[j0+3];
    float rw00 = rwl[j0],     rw01 = rwl[j0+1],     rw02 = rwl[j0+2],     rw03 = rwl[j0+3];
    float rw10 = rwl[256+j0], rw11 = rwl[256+j0+1], rw12 = rwl[256+j0+2], rw13 = rwl[256+j0+3];
    float rw20 = rwl[512+j0], rw21 = rwl[512+j0+1], rw22 = rwl[512+j0+2], rw23 = rwl[512+j0+3];
    float rw30 = rwl[768+j0], rw31 = rwl[768+j0+1], rw32 = rwl[768+j0+2], rw33 = rwl[768+j0+3];
    float4 ba0 = {0,0,0,0}, ba1 = {0,0,0,0}, ba2 = {0,0,0,0}, ba3 = {0,0,0,0};
    float4* Lrow = (float4*)Lg;
#pragma unroll 4
    for (int ii = 0; ii < 16; ii++) {
      int i = wv*16 + ii;
      float wwi = wwl[i];
      float4 lv = Lrow[i*64 + lane];
      float4 nv;
      nv.x = (1.f - wwi - wwj0)*lv.x + wwi*pj0;
      nv.y = (1.f - wwi - wwj1)*lv.y + wwi*pj1;
      nv.z = (1.f - wwi - wwj2)*lv.z + wwi*pj2;
      nv.w = (1.f - wwi - wwj3)*lv.w + wwi*pj3;
      if (j0   == i) nv.x = 0.f;
      if (j0+1 == i) nv.y = 0.f;
      if (j0+2 == i) nv.z = 0.f;
      if (j0+3 == i) nv.w = 0.f;
      Lrow[i*64 + lane] = nv;
      float f0 = nv.x*rw00 + nv.y*rw01 + nv.z*rw02 + nv.w*rw03;
      float f1 = nv.x*rw10 + nv.y*rw11 + nv.z*rw12 + nv.w*rw13;
      float f2 = nv.x*rw20 + nv.y*rw21 + nv.z*rw22 + nv.w*rw23;
      float f3 = nv.x*rw30 + nv.y*rw31 + nv.z*rw32 + nv.w*rw33;
      f0 = wsum_(f0); f1 = wsum_(f1); f2 = wsum_(f2); f3 = wsum_(f3);
      if (lane == 0) { fwdl[i] = f0; fwdl[256+i] = f1; fwdl[512+i] = f2; fwdl[768+i] = f3; }
      float ri0 = rwl[i], ri1 = rwl[256+i], ri2 = rwl[512+i], ri3 = rwl[768+i];
      ba0.x = fmaf(ri0, nv.x, ba0.x); ba0.y = fmaf(ri0, nv.y, ba0.y);
      ba0.z = fmaf(ri0, nv.z, ba0.z); ba0.w = fmaf(ri0, nv.w, ba0.w);
      ba1.x = fmaf(ri1, nv.x, ba1.x); ba1.y = fmaf(ri1, nv.y, ba1.y);
      ba1.z = fmaf(ri1, nv.z, ba1.z); ba1.w = fmaf(ri1, nv.w, ba1.w);
      ba2.x = fmaf(ri2, nv.x, ba2.x); ba2.y = fmaf(ri2, nv.y, ba2.y);
      ba2.z = fmaf(ri2, nv.z, ba2.z); ba2.w = fmaf(ri2, nv.w, ba2.w);
      ba3.x = fmaf(ri3, nv.x, ba3.x); ba3.y = fmaf(ri3, nv.y, ba3.y);
      ba3.z = fmaf(ri3, nv.z, ba3.z); ba3.w = fmaf(ri3, nv.w, ba3.w);
    }
#pragma unroll
    for (int r = 0; r < 4; r++) {
      float4 v = (r==0) ? ba0 : (r==1) ? ba1 : (r==2) ? ba2 : ba3;
      *(float4*)&bb[wv][j0] = v;
      __syncthreads();
      if (tid < 256) {
        float s = 0.f;
#pragma unroll
        for (int w2 = 0; w2 < 16; w2++) s += bb[w2][tid];
        bwdl[r*256 + tid] = s;
      }
      __syncthreads();
    }
  }

  // M update + rc logits
  {
    int n = tid >> 2, q = tid & 3;
    float wwn = wwl[n];
    float4* Mp = (float4*)(Mg + n*64 + q*16);
    float ss = 0.f, d0 = 0.f, d1 = 0.f, d2 = 0.f, d3 = 0.f;
#pragma unroll
    for (int i = 0; i < 4; i++) {
      float4 mv = Mp[i];
      int w0 = q*16 + i*4;
      float4 ev = *(const float4*)(evl + w0);
      float4 wq = *(const float4*)(wvl + w0);
      float4 nv;
      nv.x = mv.x*(1.f - wwn*ev.x) + wwn*wq.x;
      nv.y = mv.y*(1.f - wwn*ev.y) + wwn*wq.y;
      nv.z = mv.z*(1.f - wwn*ev.z) + wwn*wq.z;
      nv.w = mv.w*(1.f - wwn*ev.w) + wwn*wq.w;
      Mp[i] = nv;
      ss += nv.x*nv.x + nv.y*nv.y + nv.z*nv.z + nv.w*nv.w;
      const float* k0 = rknl + w0;
      const float* k1 = rknl + 64 + w0;
      const float* k2 = rknl + 128 + w0;
      const float* k3 = rknl + 192 + w0;
      d0 += nv.x*k0[0] + nv.y*k0[1] + nv.z*k0[2] + nv.w*k0[3];
      d1 += nv.x*k1[0] + nv.y*k1[1] + nv.z*k1[2] + nv.w*k1[3];
      d2 += nv.x*k2[0] + nv.y*k2[1] + nv.z*k2[2] + nv.w*k2[3];
      d3 += nv.x*k3[0] + nv.y*k3[1] + nv.z*k3[2] + nv.w*k3[3];
    }
    ss += __shfl_xor(ss,1,64); ss += __shfl_xor(ss,2,64);
    d0 += __shfl_xor(d0,1,64); d0 += __shfl_xor(d0,2,64);
    d1 += __shfl_xor(d1,1,64); d1 += __shfl_xor(d1,2,64);
    d2 += __shfl_xor(d2,1,64); d2 += __shfl_xor(d2,2,64);
    d3 += __shfl_xor(d3,1,64); d3 += __shfl_xor(d3,2,64);
    if (q == 0) {
      float inv = 1.f/(sqrtf(ss) + EPS_);
      rcs[n]     = oneplusf_(ifb[OFF_RB+0]) * d0 * inv;
      rcs[256+n] = oneplusf_(ifb[OFF_RB+1]) * d1 * inv;
      rcs[512+n] = oneplusf_(ifb[OFF_RB+2]) * d2 * inv;
      rcs[768+n] = oneplusf_(ifb[OFF_RB+3]) * d3 * inv;
    }
  }
  __syncthreads();
  ws[O_FWD + b*1024 + tid] = fwdl[tid];
  ws[O_BWD + b*1024 + tid] = bwdl[tid];
  ws[O_RCG + b*1024 + tid] = rcs[tid];
}

// ===================== kE: softmaxes, rw_new, rv_new =====================
__global__ void __launch_bounds__(1024)
kE(float* __restrict__ ws)
{
  const int tid = threadIdx.x, b = blockIdx.x;
  const int wv = tid >> 6, lane = tid & 63;
  const float* ifb = ws + O_IFC + b*IFS;
  const float* Mg  = ws + O_M + (size_t)b*16384;
  __shared__ float rcs[1024];
  __shared__ float rwl[1024];
  __shared__ float ps[4][256];

  rcs[tid] = ws[O_RCG + b*1024 + tid];
  __syncthreads();
  if (wv < 4) {
    float* rp = rcs + wv*256;
    float v0 = rp[lane], v1 = rp[64+lane], v2 = rp[128+lane], v3 = rp[192+lane];
    float mx = wmax_(fmaxf(fmaxf(v0,v1), fmaxf(v2,v3)));
    float e0 = expf(v0-mx), e1 = expf(v1-mx), e2 = expf(v2-mx), e3 = expf(v3-mx);
    float inv = 1.f / wsum_(e0+e1+e2+e3);
    rp[lane] = e0*inv; rp[64+lane] = e1*inv; rp[128+lane] = e2*inv; rp[192+lane] = e3*inv;
  }
  __syncthreads();
  {
    int r = tid >> 8;
    float e0 = ifb[OFF_RM + r*3+0], e1 = ifb[OFF_RM + r*3+1], e2 = ifb[OFF_RM + r*3+2];
    float mx = fmaxf(e0, fmaxf(e1, e2));
    float x0 = expf(e0-mx), x1 = expf(e1-mx), x2 = expf(e2-mx);
    float inv = 1.f/(x0+x1+x2);
    float val = (x0*ws[O_BWD + b*1024 + tid] + x1*rcs[tid] + x2*ws[O_FWD + b*1024 + tid]) * inv;
    rwl[tid] = val;
    ws[O_RW + b*1024 + tid] = val;
  }
  __syncthreads();
  {
    int w = tid & 63, r = (tid >> 6) & 3, c = tid >> 8;   // 4 k-chunks
    const float* rp = rwl + r*256 + c*64;
    float acc = 0.f;
#pragma unroll 8
    for (int n = 0; n < 64; n++) acc = fmaf(Mg[(c*64+n)*64 + w], rp[n], acc);
    ps[c][r*64 + w] = acc;
  }
  __syncthreads();
  if (tid < 256)
    ws[O_RV + b*256 + tid] = ps[0][tid] + ps[1][tid] + ps[2][tid] + ps[3][tid];
}

extern "C" void kernel_launch(void* const* d_in, const int* in_sizes, int n_in,
                              void* d_out, int out_size, void* d_ws, size_t ws_size,
                              hipStream_t stream) {
  (void)in_sizes; (void)n_in; (void)out_size; (void)ws_size;
  const float* x        = (const float*)d_in[0];
  const float* W_hid    = (const float*)d_in[1];
  const float* b_hid    = (const float*)d_in[2];
  const float* W_iface  = (const float*)d_in[3];
  const float* W_out    = (const float*)d_in[4];
  const float* W_memout = (const float*)d_in[5];
  float* outp = (float*)d_out;
  float* ws   = (float*)d_ws;

  hipLaunchKernelGGL(kInit, dim3(256), dim3(256), 0, stream, ws);
  for (int t = 0; t < TS; t++) {
    hipLaunchKernelGGL(kA, dim3(192), dim3(256), 0, stream,
                       x, W_hid, b_hid, W_memout, ws, outp, t);
    hipLaunchKernelGGL(kB, dim3(256), dim3(256), 0, stream, W_out, W_iface, ws);
    hipLaunchKernelGGL(kC, dim3(16), dim3(1024), 0, stream, ws, t);
    hipLaunchKernelGGL(kD, dim3(16), dim3(1024), 0, stream, ws, t);
    hipLaunchKernelGGL(kE, dim3(16), dim3(1024), 0, stream, ws);
  }
  // epilogue: out(T-1) via kA's out-half (h-half self-disables at t==TS)
  hipLaunchKernelGGL(kA, dim3(192), dim3(256), 0, stream,
                     x, W_hid, b_hid, W_memout, ws, outp, TS);
}

// Round 7
// 3411.607 us; speedup vs baseline: 4.8235x; 1.0136x over previous
//
#include <hip/hip_runtime.h>
#include <math.h>

#define TS 64
#define IFACE_N 471
#define EPS_ 1e-6f

// iface column offsets
#define OFF_RK 0
#define OFF_RB 256
#define OFF_WK 260
#define OFF_WB 324
#define OFF_EV 325
#define OFF_WV 389
#define OFF_FG 453
#define OFF_AG 457
#define OFF_WG 458
#define OFF_RM 459

// ws float offsets
#define O_HX  0         // 524288 : hx = x@W_hid[0:512] + b  (64*16 rows x 512)
#define O_H   524288    // 16384  : h ping-pong (2 x 16 x 512)
#define O_PRE 540672    // 16384  : pre ping-pong
#define O_RV  557056    // 8192   : rv ping-pong (2 x 16 x 256)
#define O_U   565248    // 4096
#define O_P   569344    // 4096
#define O_WW  573440    // 4096
#define O_RW  577536    // 16384
#define O_M   593920    // 262144
#define O_L   856064    // 1048576
// total 1,904,640 floats = 7.62 MB

__device__ __forceinline__ float sigmoidf_(float x){ return 1.f/(1.f+expf(-x)); }
__device__ __forceinline__ float oneplusf_(float x){ return 1.f+fmaxf(x,0.f)+log1pf(expf(-fabsf(x))); }
__device__ __forceinline__ float wsum_(float v){
#pragma unroll
  for(int off=32; off>0; off>>=1) v += __shfl_xor(v,off,64);
  return v;
}
__device__ __forceinline__ float wmax_(float v){
#pragma unroll
  for(int off=32; off>0; off>>=1) v = fmaxf(v,__shfl_xor(v,off,64));
  return v;
}

// ===================== init =====================
__global__ void __launch_bounds__(256) kInit(float* ws){
  int g = blockIdx.x*256 + threadIdx.x;          // 65536 threads
  if (g < 4096){ ws[O_U+g]=0.f; ws[O_P+g]=0.f; ws[O_WW+g]=0.f; }
  if (g < 16384) ws[O_RW+g]=0.f;
  for (int i=g;i<262144;i+=65536) ws[O_M+i]=1e-6f;
  for (int i=g;i<1048576;i+=65536) ws[O_L+i]=0.f;
}

// ===================== kPre: hx = x @ W_hid[0:512] + b ; h(0) =====================
// 256 blocks x 256 thr: block = (row-group of 8, col-half of 256)
__global__ void __launch_bounds__(256)
kPre(const float* __restrict__ x, const float* __restrict__ W_hid,
     const float* __restrict__ b_hid, float* __restrict__ ws)
{
  const int tid = threadIdx.x, blk = blockIdx.x;
  const int r0 = (blk >> 1) * 8, col = (blk & 1) * 256 + tid;
  __shared__ float xs[8][512];
  for (int i = tid; i < 8*512; i += 256) {
    int rr = i >> 9, k = i & 511;
    xs[rr][k] = x[(size_t)(r0+rr)*512 + k];
  }
  __syncthreads();
  float a0=0,a1=0,a2=0,a3=0,a4=0,a5=0,a6=0,a7=0;
  const float* Wp = W_hid + col;
#pragma unroll 4
  for (int k = 0; k < 512; k++) {
    float w = Wp[(size_t)k*512];
    a0 = fmaf(xs[0][k], w, a0); a1 = fmaf(xs[1][k], w, a1);
    a2 = fmaf(xs[2][k], w, a2); a3 = fmaf(xs[3][k], w, a3);
    a4 = fmaf(xs[4][k], w, a4); a5 = fmaf(xs[5][k], w, a5);
    a6 = fmaf(xs[6][k], w, a6); a7 = fmaf(xs[7][k], w, a7);
  }
  float bh = b_hid[col];
  float av[8] = {a0,a1,a2,a3,a4,a5,a6,a7};
#pragma unroll
  for (int i = 0; i < 8; i++) {
    int r = r0 + i;
    float v = av[i] + bh;
    ws[O_HX + (size_t)r*512 + col] = v;
    if (r < 16) ws[O_H + r*512 + col] = fmaxf(v, 0.f);   // h(0), slot 0
  }
}

// ===================== kStep: one kernel per time step =====================
// blocks 0..15  : batch blocks (full DNC step + iface + h(t+1))
// blocks 16..47 : pre(t) = h(t) @ W_out          (2 per batch)
// blocks 48..79 : out(t-1) = pre(t-1)+rv(t-1)@Wm (2 per batch)
__global__ void __launch_bounds__(1024)
kStep(const float* __restrict__ W_hid, const float* __restrict__ W_iface,
      const float* __restrict__ W_out, const float* __restrict__ W_memout,
      float* __restrict__ ws, float* __restrict__ out, int t)
{
  const int tid = threadIdx.x, blk = blockIdx.x;
  const int wv = tid >> 6, lane = tid & 63;

  __shared__ float hl[512];
  __shared__ float ifcl[480];
  __shared__ float psum[1024];
  __shared__ float ul[256], pOl[256], pNl[256], wwl[256];
  __shared__ float rwl[1024];
  __shared__ float wkn[64], rknl[256];
  __shared__ alignas(16) float evl[64], wvl[64];
  __shared__ float ssorted[256];
  __shared__ int   sidx[256];
  __shared__ float sal[256], siml[256];
  __shared__ float fwdl[1024], bwdl[1024], rcs[1024];
  __shared__ alignas(16) float bb[16][260];
  __shared__ float rvl[256];

  if (blk >= 16) {
    if (blk < 48) {                       // ---- pre(t) ----
      if (t >= TS) return;
      int q = blk - 16, b = q >> 1, half = q & 1;
      if (tid < 512) hl[tid] = ws[O_H + (t&1)*8192 + b*512 + tid];
      __syncthreads();
      int c = tid & 255, kseg = tid >> 8;
      int col = half*256 + c;
      const float* Wp = W_out + (size_t)(kseg*128)*512 + col;
      const float* hp = hl + kseg*128;
      float acc = 0.f;
#pragma unroll 8
      for (int k = 0; k < 128; k++) acc = fmaf(hp[k], Wp[(size_t)k*512], acc);
      psum[tid] = acc;
      __syncthreads();
      if (tid < 256)
        ws[O_PRE + (t&1)*8192 + b*512 + half*256 + tid]
          = psum[tid] + psum[256+tid] + psum[512+tid] + psum[768+tid];
    } else {                              // ---- out(t-1) ----
      if (t < 1) return;
      int q = blk - 48, b = q >> 1, half = q & 1;
      if (tid < 256) rvl[tid] = ws[O_RV + ((t+1)&1)*4096 + b*256 + tid];
      __syncthreads();
      int c = tid & 255, kseg = tid >> 8;
      int col = half*256 + c;
      const float* Wp = W_memout + (size_t)(kseg*64)*512 + col;
      const float* rp = rvl + kseg*64;
      float acc = 0.f;
#pragma unroll 8
      for (int k = 0; k < 64; k++) acc = fmaf(rp[k], Wp[(size_t)k*512], acc);
      psum[tid] = acc;
      __syncthreads();
      if (tid < 256) {
        int col2 = half*256 + tid;
        out[(size_t)(t-1)*8192 + b*512 + col2]
          = ws[O_PRE + ((t+1)&1)*8192 + b*512 + col2]
          + psum[tid] + psum[256+tid] + psum[512+tid] + psum[768+tid];
      }
    }
    return;
  }

  // =================== batch block ===================
  if (t >= TS) return;
  const int b = blk;
  float* Mg = ws + O_M + (size_t)b*16384;
  float* Lg = ws + O_L + (size_t)b*65536;

  // ---- load state ----
  if (tid < 512) hl[tid] = ws[O_H + (t&1)*8192 + b*512 + tid];
  rwl[tid] = ws[O_RW + b*1024 + tid];
  if (tid < 256)       ul[tid]       = ws[O_U  + b*256 + tid];
  else if (tid < 512)  pOl[tid-256]  = ws[O_P  + b*256 + tid-256];
  else if (tid < 768)  wwl[tid-512]  = ws[O_WW + b*256 + tid-512];
  __syncthreads();

  // ---- iface = h @ W_iface (coalesced col-major, k-split 2) ----
  {
    int col = tid & 511, kseg = tid >> 9;
    float acc = 0.f;
    if (col < IFACE_N) {
      const float* Wp = W_iface + (size_t)(kseg*256)*IFACE_N + col;
      const float* hp = hl + kseg*256;
#pragma unroll 8
      for (int k = 0; k < 256; k++) acc = fmaf(hp[k], Wp[(size_t)k*IFACE_N], acc);
    }
    psum[tid] = acc;
  }
  __syncthreads();
  if (tid < IFACE_N) ifcl[tid] = psum[tid] + psum[512+tid];
  __syncthreads();

  // ---- usage update + key norms + gate vectors ----
  if (tid < 256) {
    float ret = 1.f;
#pragma unroll
    for (int r = 0; r < 4; r++) {
      float fg = sigmoidf_(ifcl[OFF_FG + r]);
      ret *= (1.f - fg * rwl[r*256 + tid]);
    }
    float uo = ul[tid], wo = wwl[tid];
    ul[tid] = (uo + wo - uo*wo) * ret;
  } else if (tid >= 448 && tid < 512) {              // wave 7: wk norm
    float kv = ifcl[OFF_WK + lane];
    float ss = wsum_(kv*kv);
    wkn[lane] = kv / (sqrtf(ss) + EPS_);
  } else if (tid >= 512 && tid < 768) {              // waves 8..11: rk norms
    int r = wv - 8;
    float kv = ifcl[OFF_RK + r*64 + lane];
    float ss = wsum_(kv*kv);
    rknl[r*64 + lane] = kv / (sqrtf(ss) + EPS_);
  } else if (tid >= 768 && tid < 832) {              // wave 12: erase vec
    evl[lane] = sigmoidf_(ifcl[OFF_EV + lane]);
  } else if (tid >= 832 && tid < 896) {              // wave 13: write vec
    wvl[lane] = ifcl[OFF_WV + lane];
  }
  __syncthreads();

  // ---- stable rank argsort + cumprod alloc ----
  {
    int n = tid >> 2, q = tid & 3;
    float un = ul[n];
    const float* sp = ul + q*64;
    int cnt = 0;
#pragma unroll 8
    for (int m = 0; m < 64; m++) {
      float um = sp[m];
      int gm = q*64 + m;
      cnt += (um < un || (um == un && gm < n)) ? 1 : 0;
    }
    cnt += __shfl_xor(cnt, 1, 64);
    cnt += __shfl_xor(cnt, 2, 64);
    if (q == 0) { ssorted[cnt] = un; sidx[cnt] = n; }
  }
  __syncthreads();
  if (wv == 0) {
    float carry = 1.f;
#pragma unroll
    for (int c2 = 0; c2 < 4; c2++) {
      float v0 = ssorted[c2*64 + lane];
      float v = v0;
#pragma unroll
      for (int off = 1; off < 64; off <<= 1) {
        float uu = __shfl_up(v, off, 64);
        if (lane >= off) v *= uu;
      }
      float e = __shfl_up(v, 1, 64);
      if (lane == 0) e = 1.f;
      sal[sidx[c2*64 + lane]] = (1.f - v0) * e * carry;
      carry *= __shfl(v, 63, 64);
    }
  }
  __syncthreads();

  // ---- write content weights over OLD M ----
  {
    int n = tid >> 2, q = tid & 3;
    const float4* Mp = (const float4*)(Mg + n*64 + q*16);
    float ss = 0.f, dt = 0.f;
#pragma unroll
    for (int i = 0; i < 4; i++) {
      float4 mv = Mp[i];
      const float* kp = wkn + q*16 + i*4;
      ss += mv.x*mv.x + mv.y*mv.y + mv.z*mv.z + mv.w*mv.w;
      dt += mv.x*kp[0] + mv.y*kp[1] + mv.z*kp[2] + mv.w*kp[3];
    }
    ss += __shfl_xor(ss,1,64); ss += __shfl_xor(ss,2,64);
    dt += __shfl_xor(dt,1,64); dt += __shfl_xor(dt,2,64);
    if (q == 0) {
      float wb = oneplusf_(ifcl[OFF_WB]);
      siml[n] = wb * dt / (sqrtf(ss) + EPS_);
    }
  }
  __syncthreads();
  if (tid < 256) {
    float v0 = siml[lane], v1 = siml[64+lane], v2 = siml[128+lane], v3 = siml[192+lane];
    float mx = wmax_(fmaxf(fmaxf(v0,v1), fmaxf(v2,v3)));
    float ssum = wsum_(expf(v0-mx)+expf(v1-mx)+expf(v2-mx)+expf(v3-mx));
    float cw = expf(siml[tid]-mx) / ssum;
    float ag = sigmoidf_(ifcl[OFF_AG]);
    float wg = sigmoidf_(ifcl[OFF_WG]);
    wwl[tid] = wg * (ag*sal[tid] + (1.f-ag)*cw);      // NEW ww (old consumed above)
    ssorted[tid] = wwl[tid];                          // reuse as scratch
  }
  __syncthreads();
  if (tid < 256) {
    float s4 = ssorted[lane] + ssorted[64+lane] + ssorted[128+lane] + ssorted[192+lane];
    float wws = wsum_(s4);
    pNl[tid] = (1.f - wws)*pOl[tid] + wwl[tid];
  }
  __syncthreads();

  // ---- L update + fwd + bwd ----
  {
    int j0 = lane*4;
    float wwj0 = wwl[j0], wwj1 = wwl[j0+1], wwj2 = wwl[j0+2], wwj3 = wwl[j0+3];
    float pj0 = pOl[j0], pj1 = pOl[j0+1], pj2 = pOl[j0+2], pj3 = pOl[j0+3];
    float rw00 = rwl[j0],     rw01 = rwl[j0+1],     rw02 = rwl[j0+2],     rw03 = rwl[j0+3];
    float rw10 = rwl[256+j0], rw11 = rwl[256+j0+1], rw12 = rwl[256+j0+2], rw13 = rwl[256+j0+3];
    float rw20 = rwl[512+j0], rw21 = rwl[512+j0+1], rw22 = rwl[512+j0+2], rw23 = rwl[512+j0+3];
    float rw30 = rwl[768+j0], rw31 = rwl[768+j0+1], rw32 = rwl[768+j0+2], rw33 = rwl[768+j0+3];
    float4 ba0 = {0,0,0,0}, ba1 = {0,0,0,0}, ba2 = {0,0,0,0}, ba3 = {0,0,0,0};
    float4* Lrow = (float4*)Lg;
#pragma unroll 4
    for (int ii = 0; ii < 16; ii++) {
      int i = wv*16 + ii;
      float wwi = wwl[i];
      float4 lv = Lrow[i*64 + lane];
      float4 nv;
      nv.x = (1.f - wwi - wwj0)*lv.x + wwi*pj0;
      nv.y = (1.f - wwi - wwj1)*lv.y + wwi*pj1;
      nv.z = (1.f - wwi - wwj2)*lv.z + wwi*pj2;
      nv.w = (1.f - wwi - wwj3)*lv.w + wwi*pj3;
      if (j0   == i) nv.x = 0.f;
      if (j0+1 == i) nv.y = 0.f;
      if (j0+2 == i) nv.z = 0.f;
      if (j0+3 == i) nv.w = 0.f;
      Lrow[i*64 + lane] = nv;
      float f0 = nv.x*rw00 + nv.y*rw01 + nv.z*rw02 + nv.w*rw03;
      float f1 = nv.x*rw10 + nv.y*rw11 + nv.z*rw12 + nv.w*rw13;
      float f2 = nv.x*rw20 + nv.y*rw21 + nv.z*rw22 + nv.w*rw23;
      float f3 = nv.x*rw30 + nv.y*rw31 + nv.z*rw32 + nv.w*rw33;
      f0 = wsum_(f0); f1 = wsum_(f1); f2 = wsum_(f2); f3 = wsum_(f3);
      if (lane == 0) { fwdl[i] = f0; fwdl[256+i] = f1; fwdl[512+i] = f2; fwdl[768+i] = f3; }
      float ri0 = rwl[i], ri1 = rwl[256+i], ri2 = rwl[512+i], ri3 = rwl[768+i];
      ba0.x = fmaf(ri0, nv.x, ba0.x); ba0.y = fmaf(ri0, nv.y, ba0.y);
      ba0.z = fmaf(ri0, nv.z, ba0.z); ba0.w = fmaf(ri0, nv.w, ba0.w);
      ba1.x = fmaf(ri1, nv.x, ba1.x); ba1.y = fmaf(ri1, nv.y, ba1.y);
      ba1.z = fmaf(ri1, nv.z, ba1.z); ba1.w = fmaf(ri1, nv.w, ba1.w);
      ba2.x = fmaf(ri2, nv.x, ba2.x); ba2.y = fmaf(ri2, nv.y, ba2.y);
      ba2.z = fmaf(ri2, nv.z, ba2.z); ba2.w = fmaf(ri2, nv.w, ba2.w);
      ba3.x = fmaf(ri3, nv.x, ba3.x); ba3.y = fmaf(ri3, nv.y, ba3.y);
      ba3.z = fmaf(ri3, nv.z, ba3.z); ba3.w = fmaf(ri3, nv.w, ba3.w);
    }
#pragma unroll
    for (int r = 0; r < 4; r++) {
      float4 v = (r==0) ? ba0 : (r==1) ? ba1 : (r==2) ? ba2 : ba3;
      *(float4*)&bb[wv][j0] = v;
      __syncthreads();
      if (tid < 256) {
        float s = 0.f;
#pragma unroll
        for (int w2 = 0; w2 < 16; w2++) s += bb[w2][tid];
        bwdl[r*256 + tid] = s;
      }
      __syncthreads();
    }
  }

  // ---- M update + rc logits (NEW M) ----
  {
    int n = tid >> 2, q = tid & 3;
    float wwn = wwl[n];
    float4* Mp = (float4*)(Mg + n*64 + q*16);
    float ss = 0.f, d0 = 0.f, d1 = 0.f, d2 = 0.f, d3 = 0.f;
#pragma unroll
    for (int i = 0; i < 4; i++) {
      float4 mv = Mp[i];
      int w0 = q*16 + i*4;
      float4 ev = *(const float4*)(evl + w0);
      float4 wq = *(const float4*)(wvl + w0);
      float4 nv;
      nv.x = mv.x*(1.f - wwn*ev.x) + wwn*wq.x;
      nv.y = mv.y*(1.f - wwn*ev.y) + wwn*wq.y;
      nv.z = mv.z*(1.f - wwn*ev.z) + wwn*wq.z;
      nv.w = mv.w*(1.f - wwn*ev.w) + wwn*wq.w;
      Mp[i] = nv;
      ss += nv.x*nv.x + nv.y*nv.y + nv.z*nv.z + nv.w*nv.w;
      const float* k0 = rknl + w0;
      const float* k1 = rknl + 64 + w0;
      const float* k2 = rknl + 128 + w0;
      const float* k3 = rknl + 192 + w0;
      d0 += nv.x*k0[0] + nv.y*k0[1] + nv.z*k0[2] + nv.w*k0[3];
      d1 += nv.x*k1[0] + nv.y*k1[1] + nv.z*k1[2] + nv.w*k1[3];
      d2 += nv.x*k2[0] + nv.y*k2[1] + nv.z*k2[2] + nv.w*k2[3];
      d3 += nv.x*k3[0] + nv.y*k3[1] + nv.z*k3[2] + nv.w*k3[3];
    }
    ss += __shfl_xor(ss,1,64); ss += __shfl_xor(ss,2,64);
    d0 += __shfl_xor(d0,1,64); d0 += __shfl_xor(d0,2,64);
    d1 += __shfl_xor(d1,1,64); d1 += __shfl_xor(d1,2,64);
    d2 += __shfl_xor(d2,1,64); d2 += __shfl_xor(d2,2,64);
    d3 += __shfl_xor(d3,1,64); d3 += __shfl_xor(d3,2,64);
    if (q == 0) {
      float inv = 1.f/(sqrtf(ss) + EPS_);
      rcs[n]     = oneplusf_(ifcl[OFF_RB+0]) * d0 * inv;
      rcs[256+n] = oneplusf_(ifcl[OFF_RB+1]) * d1 * inv;
      rcs[512+n] = oneplusf_(ifcl[OFF_RB+2]) * d2 * inv;
      rcs[768+n] = oneplusf_(ifcl[OFF_RB+3]) * d3 * inv;
    }
  }
  __syncthreads();

  // ---- rc softmax ----
  if (wv < 4) {
    float* rp = rcs + wv*256;
    float v0 = rp[lane], v1 = rp[64+lane], v2 = rp[128+lane], v3 = rp[192+lane];
    float mx = wmax_(fmaxf(fmaxf(v0,v1), fmaxf(v2,v3)));
    float e0 = expf(v0-mx), e1 = expf(v1-mx), e2 = expf(v2-mx), e3 = expf(v3-mx);
    float inv = 1.f / wsum_(e0+e1+e2+e3);
    rp[lane] = e0*inv; rp[64+lane] = e1*inv; rp[128+lane] = e2*inv; rp[192+lane] = e3*inv;
  }
  __syncthreads();

  // ---- rw_new ----
  {
    int r = tid >> 8;
    float e0 = ifcl[OFF_RM + r*3+0], e1 = ifcl[OFF_RM + r*3+1], e2 = ifcl[OFF_RM + r*3+2];
    float mx = fmaxf(e0, fmaxf(e1, e2));
    float x0 = expf(e0-mx), x1 = expf(e1-mx), x2 = expf(e2-mx);
    float inv = 1.f/(x0+x1+x2);
    float val = (x0*bwdl[tid] + x1*rcs[tid] + x2*fwdl[tid]) * inv;
    rwl[tid] = val;
    ws[O_RW + b*1024 + tid] = val;
  }
  __syncthreads();

  // ---- rv_new ----
  {
    int w = tid & 63, r = (tid >> 6) & 3, c = tid >> 8;
    const float* rp = rwl + r*256 + c*64;
    float acc = 0.f;
#pragma unroll 8
    for (int n = 0; n < 64; n++) acc = fmaf(Mg[(c*64+n)*64 + w], rp[n], acc);
    psum[c*256 + r*64 + w] = acc;
  }
  __syncthreads();
  if (tid < 256)
    rvl[tid] = psum[tid] + psum[256+tid] + psum[512+tid] + psum[768+tid];
  __syncthreads();

  // ---- h(t+1) = relu(hx(t+1) + rv @ W_hid[512:768]) ----
  if (t + 1 < TS) {
    int col = tid & 511, kseg = tid >> 9;
    const float* Wp = W_hid + (size_t)(512 + kseg*128)*512 + col;
    const float* rp = rvl + kseg*128;
    float acc = 0.f;
#pragma unroll 8
    for (int k = 0; k < 128; k++) acc = fmaf(rp[k], Wp[(size_t)k*512], acc);
    psum[tid] = acc;
    __syncthreads();
    if (tid < 512) {
      float v = ws[O_HX + (size_t)((t+1)*16 + b)*512 + tid] + psum[tid] + psum[512+tid];
      ws[O_H + ((t+1)&1)*8192 + b*512 + tid] = fmaxf(v, 0.f);
    }
  }

  // ---- state writeback ----
  if (tid < 256) {
    ws[O_U  + b*256 + tid] = ul[tid];
    ws[O_P  + b*256 + tid] = pNl[tid];
    ws[O_WW + b*256 + tid] = wwl[tid];
    ws[O_RV + (t&1)*4096 + b*256 + tid] = rvl[tid];
  }
}

extern "C" void kernel_launch(void* const* d_in, const int* in_sizes, int n_in,
                              void* d_out, int out_size, void* d_ws, size_t ws_size,
                              hipStream_t stream) {
  (void)in_sizes; (void)n_in; (void)out_size; (void)ws_size;
  const float* x        = (const float*)d_in[0];
  const float* W_hid    = (const float*)d_in[1];
  const float* b_hid    = (const float*)d_in[2];
  const float* W_iface  = (const float*)d_in[3];
  const float* W_out    = (const float*)d_in[4];
  const float* W_memout = (const float*)d_in[5];
  float* outp = (float*)d_out;
  float* ws   = (float*)d_ws;

  hipLaunchKernelGGL(kInit, dim3(256), dim3(256), 0, stream, ws);
  hipLaunchKernelGGL(kPre,  dim3(256), dim3(256), 0, stream, x, W_hid, b_hid, ws);
  for (int t = 0; t < TS; t++)
    hipLaunchKernelGGL(kStep, dim3(80), dim3(1024), 0, stream,
                       W_hid, W_iface, W_out, W_memout, ws, outp, t);
  // epilogue: out(63) only (batch/pre roles self-disable at t==TS)
  hipLaunchKernelGGL(kStep, dim3(80), dim3(1024), 0, stream,
                     W_hid, W_iface, W_out, W_memout, ws, outp, TS);
}